// Round 7
// baseline (236.402 us; speedup 1.0000x reference)
//
#include <hip/hip_runtime.h>

#define S_LEN 2048
#define HID_DIM 2048
#define NG 8
#define NHQ 4
#define DH 64
#define QKV_N 3072   // G*(HQ+2)*D
#define ATT_SCALE 0.125f

typedef short short8 __attribute__((ext_vector_type(8)));
typedef float f32x4 __attribute__((ext_vector_type(4)));
typedef float f32x16 __attribute__((ext_vector_type(16)));
typedef unsigned short ushort_t;

__device__ __forceinline__ unsigned short f2bf(float f) {
  unsigned u = __builtin_bit_cast(unsigned, f);
  u += 0x7fffu + ((u >> 16) & 1u);   // RNE
  return (unsigned short)(u >> 16);
}

__device__ __forceinline__ void mfma16(f32x4& d, short8 a, short8 b) {
  asm volatile("v_mfma_f32_16x16x32_bf16 %0, %1, %2, %0" : "+v"(d) : "v"(a), "v"(b));
}

__device__ __forceinline__ void mfma32(f32x16& d, short8 a, short8 b) {
  asm volatile("v_mfma_f32_32x32x16_bf16 %0, %1, %2, %0" : "+v"(d) : "v"(a), "v"(b));
}

#define GLDS16(gp, lp) __builtin_amdgcn_global_load_lds( \
    (__attribute__((address_space(1))) void*)(gp),       \
    (__attribute__((address_space(3))) void*)(lp), 16, 0, 0)

// ---------------- fp32 -> bf16 convert (vectorized) ----------------
__global__ __launch_bounds__(256) void cvt_bf16_k(const float* __restrict__ in,
                                                  ushort_t* __restrict__ out, int n4) {
  int i = blockIdx.x * 256 + threadIdx.x;
  if (i >= n4) return;
  float4 v = ((const float4*)in)[i];
  ushort4 o;
  o.x = f2bf(v.x); o.y = f2bf(v.y); o.z = f2bf(v.z); o.w = f2bf(v.w);
  ((ushort4*)out)[i] = o;
}

// ---------------- fp32 -> bf16 transpose: out[C][R] = in[R][C]^T ----------------
__global__ __launch_bounds__(256) void tcvt_k(const float* __restrict__ in,
                                              ushort_t* __restrict__ out, int R, int C) {
  __shared__ ushort_t t[32][33];
  int bx = blockIdx.x * 32, by = blockIdx.y * 32;
  int tx = threadIdx.x & 31, ty = threadIdx.x >> 5;
  for (int j = ty; j < 32; j += 8)
    t[j][tx] = f2bf(in[(long)(by + j) * C + bx + tx]);
  __syncthreads();
  for (int j = ty; j < 32; j += 8)
    out[(long)(bx + j) * R + by + tx] = t[tx][j];
}

// ---------------- bf16 MFMA GEMM: C(MxN) = A(MxK) * BT(NxK)^T, C fp32 ----------------
__global__ __launch_bounds__(256) void gemm_bt_k(const ushort_t* __restrict__ A,
                                                 const ushort_t* __restrict__ BT,
                                                 float* __restrict__ C,
                                                 int M, int N, int K) {
  __shared__ __align__(16) ushort_t Al[128 * 32];
  __shared__ __align__(16) ushort_t Bl[128 * 32];
  const int tid = threadIdx.x;
  const int w = tid >> 6, lane = tid & 63;
  const int m0 = blockIdx.y * 128, n0 = blockIdx.x * 128;

  const int srow = lane >> 2;
  const int skk = (lane & 3) << 3;
  const ushort_t* Ag = A + (long)(m0 + 32 * w + srow) * K + skk;
  const ushort_t* Bg = BT + (long)(n0 + 32 * w + srow) * K + skk;
  ushort_t* Als = &Al[(32 * w) * 32];
  ushort_t* Bls = &Bl[(32 * w) * 32];

  f32x4 acc[4][4];
#pragma unroll
  for (int i = 0; i < 4; ++i)
#pragma unroll
    for (int j = 0; j < 4; ++j) acc[i][j] = (f32x4){0.f, 0.f, 0.f, 0.f};

  const int fr = lane & 15;
  const int kq = (lane >> 4) << 3;
  const int wm = w >> 1, wn = w & 1;

  for (int kt = 0; kt < K; kt += 32) {
    GLDS16(Ag, Als);
    GLDS16(Ag + 16 * K, Als + 16 * 32);
    GLDS16(Bg, Bls);
    GLDS16(Bg + 16 * K, Bls + 16 * 32);
    Ag += 32; Bg += 32;
    __syncthreads();
    short8 af[4], bfr[4];
#pragma unroll
    for (int mf = 0; mf < 4; ++mf)
      af[mf] = *(const short8*)&Al[(64 * wm + 16 * mf + fr) * 32 + kq];
#pragma unroll
    for (int nf = 0; nf < 4; ++nf)
      bfr[nf] = *(const short8*)&Bl[(64 * wn + 16 * nf + fr) * 32 + kq];
#pragma unroll
    for (int mf = 0; mf < 4; ++mf)
#pragma unroll
      for (int nf = 0; nf < 4; ++nf)
        mfma16(acc[mf][nf], af[mf], bfr[nf]);
    __syncthreads();
  }

  const int crow = m0 + 64 * wm + 4 * (lane >> 4);
  const int ccol = n0 + 64 * wn + fr;
#pragma unroll
  for (int mf = 0; mf < 4; ++mf)
#pragma unroll
    for (int nf = 0; nf < 4; ++nf)
#pragma unroll
      for (int r = 0; r < 4; ++r)
        C[(long)(crow + 16 * mf + r) * N + ccol + 16 * nf] = acc[mf][nf][r];
}

// ---------------- fused RoPE + bf16 convert, head-major layouts ----------------
__global__ __launch_bounds__(256) void rope_cvt_k(const float* __restrict__ qkv,
                                                  const float* __restrict__ cosb,
                                                  const float* __restrict__ sinb,
                                                  ushort_t* __restrict__ Qbf,
                                                  ushort_t* __restrict__ Kbf) {
  int p = blockIdx.x * 256 + threadIdx.x;  // 0..1279
  int s = blockIdx.y;
  int i = p & 31;
  int hh = p >> 5;                         // 0..39
  int g = hh / 5, h = hh % 5;              // h: q0..q3, k
  const float* base = qkv + (long)s * QKV_N + g * 384 + h * 64;
  float c = cosb[s * 32 + i], sn = sinb[s * 32 + i];
  float x1 = base[i], x2 = base[i + 32];
  float y1 = x1 * c - x2 * sn;
  float y2 = x2 * c + x1 * sn;
  if (h < 4) {
    ushort_t* dst = Qbf + ((long)(g * 4 + h) * 2048 + s) * 64;
    dst[i] = f2bf(y1 * ATT_SCALE);
    dst[i + 32] = f2bf(y2 * ATT_SCALE);
  } else {
    ushort_t* dst = Kbf + ((long)g * 2048 + s) * 64;
    dst[i] = f2bf(y1);
    dst[i + 32] = f2bf(y2);
  }
}

// ---------------- V transpose to bf16: Vt[g][d][s] ----------------
__global__ __launch_bounds__(256) void vtrans_k(const float* __restrict__ qkv,
                                                ushort_t* __restrict__ Vt) {
  __shared__ ushort_t t[64][65];
  int s0 = blockIdx.x * 64, g = blockIdx.y;
  for (int idx = threadIdx.x; idx < 4096; idx += 256) {
    int r = idx >> 6, d = idx & 63;
    t[d][r] = f2bf(qkv[(long)(s0 + r) * QKV_N + g * 384 + 320 + d]);
  }
  __syncthreads();
  for (int idx = threadIdx.x; idx < 4096; idx += 256) {
    int d = idx >> 6, c = idx & 63;
    Vt[((long)g * 64 + d) * 2048 + s0 + c] = t[d][c];
  }
}

// ---------------- bf16 MFMA flash attention v7: swapped-QK^T, P via LDS ----
// = attn6 structure (32x32 MFMA, lane-local softmax rows, barrier-free loop,
// direct-global K/V with prefetch) but P routed through a per-wave swizzled
// LDS buffer so PV's B-operand is LOAD-placed (permutation-proof), replacing
// the in-register shuffle construction (the round-6 bisection suspect).
// P layout: row q (=cq) stride 128B; pair (t even,t odd) packed in u32 at
// byte (2t)^((cq&7)<<4); B-frag read: short8 at byte (32c+16h2)^((cq&7)<<4).
__global__ __launch_bounds__(256, 2) void attn7_k(const ushort_t* __restrict__ Qbf,
                                                  const ushort_t* __restrict__ Kbf,
                                                  const ushort_t* __restrict__ Vt,
                                                  ushort_t* __restrict__ outb) {
  __shared__ __align__(16) char Pl[4][4096];       // per-wave P: 32 rows x 128 B
  __shared__ __align__(16) ushort_t Ot[4][32 * 72];
  const int b = blockIdx.x;
  const int gh = b >> 4;                      // gh-major: L2 locality
  const int jj = b & 15;
  const int qb = (jj < 8) ? (15 - jj) : (jj - 8);  // heavy blocks first
  const int g = gh >> 2;
  const int w = threadIdx.x >> 6, l = threadIdx.x & 63;
  const int cq = l & 31, h2 = l >> 5;
  const int q0w = qb * 128 + 32 * w;
  const int q = q0w + cq;

  const ushort_t* Qh = Qbf + (size_t)gh * 2048 * 64;
  const ushort_t* Kh = Kbf + (size_t)g * 2048 * 64;
  const ushort_t* Vh = Vt + (size_t)g * 64 * 2048;
  char* Pq = &Pl[w][0] + cq * 128;            // this lane's P row (q = cq)
  const int swz = (cq & 7) << 4;

  // Q B-frags (held all loop): bq[kk] = Q[q][16kk + 8h2 .. +8]
  short8 bq0 = *(const short8*)&Qh[(size_t)q * 64 + 0 + h2 * 8];
  short8 bq1 = *(const short8*)&Qh[(size_t)q * 64 + 16 + h2 * 8];
  short8 bq2 = *(const short8*)&Qh[(size_t)q * 64 + 32 + h2 * 8];
  short8 bq3 = *(const short8*)&Qh[(size_t)q * 64 + 48 + h2 * 8];

  f32x16 oT0 = (f32x16){0.f,0.f,0.f,0.f,0.f,0.f,0.f,0.f,0.f,0.f,0.f,0.f,0.f,0.f,0.f,0.f};
  f32x16 oT1 = oT0;
  float m = -1e30f, lsum = 0.f;

  const int nw = (q0w >> 6) + 1;   // tiles this wave needs

  short8 kA[8], kB[8], vC[8];

#define ISSUE_K(KS, ti) { _Pragma("unroll") \
    for (int f = 0; f < 8; ++f) { \
      const int tt = f >> 2, kk = f & 3; \
      KS[f] = *(const short8*)&Kh[((size_t)((ti) * 64 + 32 * tt + cq)) * 64 + kk * 16 + h2 * 8]; } }

#define ISSUE_V(VS, ti) { _Pragma("unroll") \
    for (int f = 0; f < 8; ++f) { \
      const int dt = f >> 2, c = f & 3; \
      VS[f] = *(const short8*)&Vh[((size_t)(32 * dt + cq)) * 2048 + (ti) * 64 + c * 16 + h2 * 8]; } }

#define COMPUTE(KS, VS, t0) { \
    f32x16 s0 = (f32x16){0.f,0.f,0.f,0.f,0.f,0.f,0.f,0.f,0.f,0.f,0.f,0.f,0.f,0.f,0.f,0.f}; \
    f32x16 s1 = s0; \
    mfma32(s0, KS[0], bq0); mfma32(s1, KS[4], bq0); \
    mfma32(s0, KS[1], bq1); mfma32(s1, KS[5], bq1); \
    mfma32(s0, KS[2], bq2); mfma32(s1, KS[6], bq2); \
    mfma32(s0, KS[3], bq3); mfma32(s1, KS[7], bq3); \
    if ((t0) + 63 > q0w) { \
      _Pragma("unroll") \
      for (int r = 0; r < 16; ++r) { \
        const int trow = (t0) + (r & 3) + 8 * (r >> 2) + 4 * h2; \
        if (trow > q) s0[r] = -1e30f; \
        if (trow + 32 > q) s1[r] = -1e30f; } } \
    float pm = s0[0]; \
    _Pragma("unroll") for (int r = 1; r < 16; ++r) pm = fmaxf(pm, s0[r]); \
    _Pragma("unroll") for (int r = 0; r < 16; ++r) pm = fmaxf(pm, s1[r]); \
    pm = fmaxf(pm, __shfl_xor(pm, 32, 64)); \
    const float mn = fmaxf(m, pm); \
    const float corr = __expf(m - mn); \
    m = mn; \
    float ls = 0.f; \
    _Pragma("unroll") for (int r = 0; r < 16; ++r) { s0[r] = __expf(s0[r] - mn); ls += s0[r]; } \
    _Pragma("unroll") for (int r = 0; r < 16; ++r) { s1[r] = __expf(s1[r] - mn); ls += s1[r]; } \
    ls += __shfl_xor(ls, 32, 64); \
    lsum = lsum * corr + ls; \
    oT0 *= corr; oT1 *= corr; \
    _Pragma("unroll") \
    for (int p = 0; p < 8; ++p) { \
      const int tb = 2 * ((2 * p & 3) + 8 * (2 * p >> 2) + 4 * h2); \
      unsigned w0 = (unsigned)f2bf(s0[2 * p]) | ((unsigned)f2bf(s0[2 * p + 1]) << 16); \
      unsigned w1 = (unsigned)f2bf(s1[2 * p]) | ((unsigned)f2bf(s1[2 * p + 1]) << 16); \
      *(unsigned*)(Pq + (tb ^ swz)) = w0; \
      *(unsigned*)(Pq + ((tb + 64) ^ swz)) = w1; \
    } \
    asm volatile("" ::: "memory"); \
    _Pragma("unroll") \
    for (int c = 0; c < 4; ++c) { \
      short8 pf = *(const short8*)(Pq + ((32 * c + 16 * h2) ^ swz)); \
      mfma32(oT0, VS[c], pf); \
      mfma32(oT1, VS[4 + c], pf); \
    } \
    asm volatile("" ::: "memory"); }

  ISSUE_K(kA, 0);
  int it = 0;
  while (true) {
    ISSUE_V(vC, it);                      // V first; K prefetch stays in flight
    if (it + 1 < nw) ISSUE_K(kB, it + 1);
    COMPUTE(kA, vC, it * 64);
    ++it; if (it == nw) break;
    ISSUE_V(vC, it);
    if (it + 1 < nw) ISSUE_K(kA, it + 1);
    COMPUTE(kB, vC, it * 64);
    ++it; if (it == nw) break;
  }

  // ---- epilogue: normalize, transpose via per-wave LDS, coalesced store ----
  {
    const float inv = 1.f / lsum;
    ushort_t* ow = &Ot[w][0];
#pragma unroll
    for (int r = 0; r < 16; ++r) {
      const int d0 = (r & 3) + 8 * (r >> 2) + 4 * h2;
      ow[cq * 72 + d0] = f2bf(oT0[r] * inv);
      ow[cq * 72 + d0 + 32] = f2bf(oT1[r] * inv);
    }
    asm volatile("" ::: "memory");
    const int rr = l >> 1, hh = l & 1;   // wave-internal transpose read
#pragma unroll
    for (int ch = 0; ch < 4; ++ch) {
      short8 vrow = *(const short8*)&ow[rr * 72 + hh * 32 + ch * 8];
      *(short8*)&outb[((size_t)(q0w + rr)) * HID_DIM + gh * 64 + hh * 32 + ch * 8] = vrow;
    }
  }
#undef ISSUE_K
#undef ISSUE_V
#undef COMPUTE
}

extern "C" void kernel_launch(void* const* d_in, const int* in_sizes, int n_in,
                              void* d_out, int out_size, void* d_ws, size_t ws_size,
                              hipStream_t stream) {
  const float* X    = (const float*)d_in[0];  // 2048x2048
  const float* cosb = (const float*)d_in[1];  // 2048x32
  const float* sinb = (const float*)d_in[2];  // 2048x32
  const float* Wqkv = (const float*)d_in[3];  // 2048x3072
  const float* Wd   = (const float*)d_in[4];  // 2048x2048
  float* out = (float*)d_out;                 // 2048x2048 fp32

  char* ws = (char*)d_ws;
  ushort_t* Xbf   = (ushort_t*)ws;
  ushort_t* WqkvT = Xbf + (size_t)2048 * 2048;
  ushort_t* WdT   = WqkvT + (size_t)3072 * 2048;
  float*    qkv   = (float*)(WdT + (size_t)2048 * 2048);
  ushort_t* Qbf   = Xbf;
  ushort_t* Kbf   = WqkvT;
  ushort_t* Vt    = WqkvT + (size_t)NG * 2048 * 64;
  ushort_t* attnO = (ushort_t*)qkv;

  cvt_bf16_k<<<4096, 256, 0, stream>>>(X, Xbf, (2048 * 2048) / 4);
  tcvt_k<<<dim3(3072 / 32, 2048 / 32), 256, 0, stream>>>(Wqkv, WqkvT, 2048, 3072);
  tcvt_k<<<dim3(2048 / 32, 2048 / 32), 256, 0, stream>>>(Wd, WdT, 2048, 2048);

  // qkv = X @ Wqkv  (M=2048, N=3072, K=2048)
  gemm_bt_k<<<dim3(3072 / 128, 2048 / 128), 256, 0, stream>>>(Xbf, WqkvT, qkv,
                                                              2048, 3072, 2048);
  rope_cvt_k<<<dim3(5, S_LEN), 256, 0, stream>>>(qkv, cosb, sinb, Qbf, Kbf);
  vtrans_k<<<dim3(S_LEN / 64, NG), 256, 0, stream>>>(qkv, Vt);

  attn7_k<<<512, 256, 0, stream>>>(Qbf, Kbf, Vt, attnO);

  // out = attnO @ Wd  (M=2048, N=2048, K=2048)
  gemm_bt_k<<<dim3(2048 / 128, 2048 / 128), 256, 0, stream>>>(attnO, WdT, out,
                                                              2048, 2048, 2048);
}

// Round 8
// 193.487 us; speedup vs baseline: 1.2218x; 1.2218x over previous
//
#include <hip/hip_runtime.h>

#define S_LEN 2048
#define HID_DIM 2048
#define NG 8
#define NHQ 4
#define DH 64
#define QKV_N 3072   // G*(HQ+2)*D
#define ATT_SCALE 0.125f

typedef short short8 __attribute__((ext_vector_type(8)));
typedef float f32x4 __attribute__((ext_vector_type(4)));
typedef unsigned short ushort_t;

__device__ __forceinline__ unsigned short f2bf(float f) {
  unsigned u = __builtin_bit_cast(unsigned, f);
  u += 0x7fffu + ((u >> 16) & 1u);   // RNE
  return (unsigned short)(u >> 16);
}

__device__ __forceinline__ void mfma16(f32x4& d, short8 a, short8 b) {
  asm volatile("v_mfma_f32_16x16x32_bf16 %0, %1, %2, %0" : "+v"(d) : "v"(a), "v"(b));
}

#define GLDS16(gp, lp) __builtin_amdgcn_global_load_lds( \
    (__attribute__((address_space(1))) void*)(gp),       \
    (__attribute__((address_space(3))) void*)(lp), 16, 0, 0)

// ---------------- fp32 -> bf16 convert (vectorized) ----------------
__global__ __launch_bounds__(256) void cvt_bf16_k(const float* __restrict__ in,
                                                  ushort_t* __restrict__ out, int n4) {
  int i = blockIdx.x * 256 + threadIdx.x;
  if (i >= n4) return;
  float4 v = ((const float4*)in)[i];
  ushort4 o;
  o.x = f2bf(v.x); o.y = f2bf(v.y); o.z = f2bf(v.z); o.w = f2bf(v.w);
  ((ushort4*)out)[i] = o;
}

// ---------------- fp32 -> bf16 transpose: out[C][R] = in[R][C]^T ----------------
__global__ __launch_bounds__(256) void tcvt_k(const float* __restrict__ in,
                                              ushort_t* __restrict__ out, int R, int C) {
  __shared__ ushort_t t[32][33];
  int bx = blockIdx.x * 32, by = blockIdx.y * 32;
  int tx = threadIdx.x & 31, ty = threadIdx.x >> 5;
  for (int j = ty; j < 32; j += 8)
    t[j][tx] = f2bf(in[(long)(by + j) * C + bx + tx]);
  __syncthreads();
  for (int j = ty; j < 32; j += 8)
    out[(long)(bx + j) * R + by + tx] = t[tx][j];
}

// ---------------- bf16 MFMA GEMM: C(MxN) = A(MxK) * BT(NxK)^T, C fp32 ----------------
// 128x128 tile, BK=32, 4 waves, 16x16x32 MFMA. T3-minimum double-buffer:
// per K-step issue STAGE(next tile -> buf^1) BEFORE ds_read+MFMA of buf,
// then ONE __syncthreads (drains GLDS vmcnt + releases read buffer).
__global__ __launch_bounds__(256) void gemm_bt_k(const ushort_t* __restrict__ A,
                                                 const ushort_t* __restrict__ BT,
                                                 float* __restrict__ C,
                                                 int M, int N, int K) {
  __shared__ __align__(16) ushort_t Al[2][128 * 32];
  __shared__ __align__(16) ushort_t Bl[2][128 * 32];
  const int tid = threadIdx.x;
  const int w = tid >> 6, lane = tid & 63;
  const int m0 = blockIdx.y * 128, n0 = blockIdx.x * 128;

  // staging: wave w loads 32 rows of A-tile and of BT-tile; lane covers
  // row (32w + lane>>2), k ((lane&3)*8)  (K-contiguous, 16B per lane)
  const int srow = lane >> 2;
  const int skk = (lane & 3) << 3;
  const ushort_t* Ag = A + (long)(m0 + 32 * w + srow) * K + skk;
  const ushort_t* Bg = BT + (long)(n0 + 32 * w + srow) * K + skk;
  const int ls0 = (32 * w) * 32;
  const int ls1 = (32 * w + 16) * 32;

  f32x4 acc[4][4];
#pragma unroll
  for (int i = 0; i < 4; ++i)
#pragma unroll
    for (int j = 0; j < 4; ++j) acc[i][j] = (f32x4){0.f, 0.f, 0.f, 0.f};

  const int fr = lane & 15;
  const int kq = (lane >> 4) << 3;
  const int wm = w >> 1, wn = w & 1;

  // prologue: stage tile 0 into buf 0
  GLDS16(Ag, &Al[0][ls0]);
  GLDS16(Ag + 16 * K, &Al[0][ls1]);
  GLDS16(Bg, &Bl[0][ls0]);
  GLDS16(Bg + 16 * K, &Bl[0][ls1]);
  Ag += 32; Bg += 32;
  __syncthreads();

  int buf = 0;
  for (int kt = 0; kt < K; kt += 32) {
    if (kt + 32 < K) {  // prefetch next tile into buf^1 (in flight over compute)
      GLDS16(Ag, &Al[buf ^ 1][ls0]);
      GLDS16(Ag + 16 * K, &Al[buf ^ 1][ls1]);
      GLDS16(Bg, &Bl[buf ^ 1][ls0]);
      GLDS16(Bg + 16 * K, &Bl[buf ^ 1][ls1]);
      Ag += 32; Bg += 32;
    }
    short8 af[4], bfr[4];
#pragma unroll
    for (int mf = 0; mf < 4; ++mf)
      af[mf] = *(const short8*)&Al[buf][(64 * wm + 16 * mf + fr) * 32 + kq];
#pragma unroll
    for (int nf = 0; nf < 4; ++nf)
      bfr[nf] = *(const short8*)&Bl[buf][(64 * wn + 16 * nf + fr) * 32 + kq];
#pragma unroll
    for (int mf = 0; mf < 4; ++mf)
#pragma unroll
      for (int nf = 0; nf < 4; ++nf)
        mfma16(acc[mf][nf], af[mf], bfr[nf]);
    __syncthreads();  // drains prefetch (vmcnt) + all waves done reading buf
    buf ^= 1;
  }

  const int crow = m0 + 64 * wm + 4 * (lane >> 4);
  const int ccol = n0 + 64 * wn + fr;
#pragma unroll
  for (int mf = 0; mf < 4; ++mf)
#pragma unroll
    for (int nf = 0; nf < 4; ++nf)
#pragma unroll
      for (int r = 0; r < 4; ++r)
        C[(long)(crow + 16 * mf + r) * N + ccol + 16 * nf] = acc[mf][nf][r];
}

// ---------------- fused RoPE + bf16 convert, head-major layouts ----------------
__global__ __launch_bounds__(256) void rope_cvt_k(const float* __restrict__ qkv,
                                                  const float* __restrict__ cosb,
                                                  const float* __restrict__ sinb,
                                                  ushort_t* __restrict__ Qbf,
                                                  ushort_t* __restrict__ Kbf) {
  int p = blockIdx.x * 256 + threadIdx.x;  // 0..1279
  int s = blockIdx.y;
  int i = p & 31;
  int hh = p >> 5;                         // 0..39
  int g = hh / 5, h = hh % 5;              // h: q0..q3, k
  const float* base = qkv + (long)s * QKV_N + g * 384 + h * 64;
  float c = cosb[s * 32 + i], sn = sinb[s * 32 + i];
  float x1 = base[i], x2 = base[i + 32];
  float y1 = x1 * c - x2 * sn;
  float y2 = x2 * c + x1 * sn;
  if (h < 4) {
    ushort_t* dst = Qbf + ((long)(g * 4 + h) * 2048 + s) * 64;
    dst[i] = f2bf(y1 * ATT_SCALE);
    dst[i + 32] = f2bf(y2 * ATT_SCALE);
  } else {
    ushort_t* dst = Kbf + ((long)g * 2048 + s) * 64;
    dst[i] = f2bf(y1);
    dst[i + 32] = f2bf(y2);
  }
}

// ---------------- V transpose to bf16: Vt[g][d][s] ----------------
__global__ __launch_bounds__(256) void vtrans_k(const float* __restrict__ qkv,
                                                ushort_t* __restrict__ Vt) {
  __shared__ ushort_t t[64][65];
  int s0 = blockIdx.x * 64, g = blockIdx.y;
  for (int idx = threadIdx.x; idx < 4096; idx += 256) {
    int r = idx >> 6, d = idx & 63;
    t[d][r] = f2bf(qkv[(long)(s0 + r) * QKV_N + g * 384 + 320 + d]);
  }
  __syncthreads();
  for (int idx = threadIdx.x; idx < 4096; idx += 256) {
    int d = idx >> 6, c = idx & 63;
    Vt[((long)g * 64 + d) * 2048 + s0 + c] = t[d][c];
  }
}

// ---------------- bf16 MFMA flash attention (round-5-verified attn5) ----------
// Causal pairing: block (gh, z) processes 128-row q-block z then 15-z ->
// exactly 34 tile-steps per block, zero variance. 8 waves, double-buffered
// LDS K/V via global_load_lds (linear dest, pre-swizzled global source
// chunk c ^= row&7); ds_reads apply same XOR. Unconditional online rescale.
__global__ __launch_bounds__(512, 2) void attn5_k(const ushort_t* __restrict__ Qbf,
                                                  const ushort_t* __restrict__ Kbf,
                                                  const ushort_t* __restrict__ Vt,
                                                  ushort_t* __restrict__ outb) {
  __shared__ __align__(16) ushort_t Kl[2][64 * 64];
  __shared__ __align__(16) ushort_t Vl[2][64 * 64];
  __shared__ __align__(16) ushort_t Pl[8][1024];
  const int gh = blockIdx.x, z = blockIdx.y;
  const int g = gh >> 2;
  const int w = threadIdx.x >> 6, l = threadIdx.x & 63;
  const int li = l & 15, hi = l >> 4;

  const ushort_t* Qh = Qbf + (long)gh * 2048 * 64;
  const ushort_t* Kh = Kbf + (long)g * 2048 * 64;
  const ushort_t* Vh = Vt + (long)g * 64 * 2048;
  char* Pw = (char*)&Pl[w][0];

  const int sr = 8 * w + (l >> 3);
  const int sc = (l & 7) ^ (sr & 7);

#pragma unroll
  for (int ph = 0; ph < 2; ++ph) {
    const int qb = ph ? (15 - z) : z;          // 128-row q-block index
    const int q0 = qb * 128 + w * 16;
    const int nt = 2 * qb + 2;

    short8 aq0 = *(const short8*)&Qh[(q0 + li) * 64 + hi * 8];
    short8 aq1 = *(const short8*)&Qh[(q0 + li) * 64 + 32 + hi * 8];

    f32x4 o[4];
#pragma unroll
    for (int df = 0; df < 4; ++df) o[df] = (f32x4){0.f, 0.f, 0.f, 0.f};
    float m[4] = {-1e30f, -1e30f, -1e30f, -1e30f};
    float lsum[4] = {0.f, 0.f, 0.f, 0.f};

    // prologue: stage tile 0 into buf 0
    GLDS16(Kh + (long)sr * 64 + sc * 8,   &Kl[0][(8 * w) * 64]);
    GLDS16(Vh + (long)sr * 2048 + sc * 8, &Vl[0][(8 * w) * 64]);
    __syncthreads();

    int buf = 0;
    for (int it = 0; it < nt; ++it) {
      const int t0 = it * 64;
      if (it + 1 < nt) {  // prefetch next tile into buf^1 (stays in flight)
        const int tn = t0 + 64;
        GLDS16(Kh + (long)(tn + sr) * 64 + sc * 8,   &Kl[buf ^ 1][(8 * w) * 64]);
        GLDS16(Vh + (long)sr * 2048 + tn + sc * 8,   &Vl[buf ^ 1][(8 * w) * 64]);
      }
      if (t0 <= q0 + 15) {  // causal: this wave has live rows in this tile
        const ushort_t* kb = &Kl[buf][0];
        const ushort_t* vb = &Vl[buf][0];

        // ---- QK^T: S[16q][64t] ----
        f32x4 sf[4];
#pragma unroll
        for (int f = 0; f < 4; ++f) sf[f] = (f32x4){0.f, 0.f, 0.f, 0.f};
        __builtin_amdgcn_s_setprio(1);
#pragma unroll
        for (int f = 0; f < 4; ++f) {
          const int row = 16 * f + li;
          short8 b0 = *(const short8*)&kb[row * 64 + ((hi ^ (row & 7)) << 3)];
          short8 b1 = *(const short8*)&kb[row * 64 + (((hi + 4) ^ (row & 7)) << 3)];
          mfma16(sf[f], aq0, b0);
          mfma16(sf[f], aq1, b1);
        }
        __builtin_amdgcn_s_setprio(0);

        // ---- causal mask (diagonal tiles only) ----
        if (t0 + 63 > q0) {
#pragma unroll
          for (int f = 0; f < 4; ++f) {
            int t = t0 + 16 * f + li;
#pragma unroll
            for (int r = 0; r < 4; ++r)
              if (t > q0 + 4 * hi + r) sf[f][r] = -1e30f;
          }
        }
        // ---- online softmax (unconditional rescale) ----
        float pm[4], mn[4], corr[4];
#pragma unroll
        for (int r = 0; r < 4; ++r)
          pm[r] = fmaxf(fmaxf(sf[0][r], sf[1][r]), fmaxf(sf[2][r], sf[3][r]));
#pragma unroll
        for (int dlt = 1; dlt < 16; dlt <<= 1)
#pragma unroll
          for (int r = 0; r < 4; ++r) pm[r] = fmaxf(pm[r], __shfl_xor(pm[r], dlt, 64));
#pragma unroll
        for (int r = 0; r < 4; ++r) {
          mn[r] = fmaxf(m[r], pm[r]);
          corr[r] = __expf(m[r] - mn[r]);
          m[r] = mn[r];
        }
        float ls[4] = {0.f, 0.f, 0.f, 0.f};
#pragma unroll
        for (int f = 0; f < 4; ++f) {
          int k2 = 2 * (li + 16 * f);
#pragma unroll
          for (int r = 0; r < 4; ++r) {
            float p = __expf(sf[f][r] - mn[r]);
            ls[r] += p;
            int q = 4 * hi + r;
            *(ushort_t*)(Pw + q * 128 + (k2 ^ ((q & 7) << 4))) = f2bf(p);
          }
        }
#pragma unroll
        for (int dlt = 1; dlt < 16; dlt <<= 1)
#pragma unroll
          for (int r = 0; r < 4; ++r) ls[r] += __shfl_xor(ls[r], dlt, 64);
#pragma unroll
        for (int r = 0; r < 4; ++r) lsum[r] = lsum[r] * corr[r] + ls[r];
#pragma unroll
        for (int df = 0; df < 4; ++df)
#pragma unroll
          for (int r = 0; r < 4; ++r) o[df][r] *= corr[r];

        // ---- PV: O[16q][64d] += P[16q][64t] * Vt[64d][64t]^T ----
        __builtin_amdgcn_s_setprio(1);
#pragma unroll
        for (int kst = 0; kst < 2; ++kst) {
          short8 pa = *(const short8*)(Pw + li * 128 + (((4 * kst + hi) ^ (li & 7)) << 4));
#pragma unroll
          for (int df = 0; df < 4; ++df) {
            const int row = 16 * df + li;
            short8 bv = *(const short8*)&vb[row * 64 + (((4 * kst + hi) ^ (row & 7)) << 3)];
            mfma16(o[df], pa, bv);
          }
        }
        __builtin_amdgcn_s_setprio(0);
      }
      __syncthreads();  // drains GLDS (vmcnt) + all waves done reading buf
      buf ^= 1;
    }
    // ---- epilogue: normalize and store bf16 ----
#pragma unroll
    for (int r = 0; r < 4; ++r) {
      float inv = 1.f / lsum[r];
#pragma unroll
      for (int df = 0; df < 4; ++df)
        outb[(long)(q0 + 4 * hi + r) * HID_DIM + gh * 64 + 16 * df + li] =
            f2bf(o[df][r] * inv);
    }
  }
}

extern "C" void kernel_launch(void* const* d_in, const int* in_sizes, int n_in,
                              void* d_out, int out_size, void* d_ws, size_t ws_size,
                              hipStream_t stream) {
  const float* X    = (const float*)d_in[0];  // 2048x2048
  const float* cosb = (const float*)d_in[1];  // 2048x32
  const float* sinb = (const float*)d_in[2];  // 2048x32
  const float* Wqkv = (const float*)d_in[3];  // 2048x3072
  const float* Wd   = (const float*)d_in[4];  // 2048x2048
  float* out = (float*)d_out;                 // 2048x2048 fp32

  char* ws = (char*)d_ws;
  ushort_t* Xbf   = (ushort_t*)ws;
  ushort_t* WqkvT = Xbf + (size_t)2048 * 2048;
  ushort_t* WdT   = WqkvT + (size_t)3072 * 2048;
  float*    qkv   = (float*)(WdT + (size_t)2048 * 2048);
  ushort_t* Qbf   = Xbf;
  ushort_t* Kbf   = WqkvT;
  ushort_t* Vt    = WqkvT + (size_t)NG * 2048 * 64;
  ushort_t* attnO = (ushort_t*)qkv;

  cvt_bf16_k<<<4096, 256, 0, stream>>>(X, Xbf, (2048 * 2048) / 4);
  tcvt_k<<<dim3(3072 / 32, 2048 / 32), 256, 0, stream>>>(Wqkv, WqkvT, 2048, 3072);
  tcvt_k<<<dim3(2048 / 32, 2048 / 32), 256, 0, stream>>>(Wd, WdT, 2048, 2048);

  // qkv = X @ Wqkv  (M=2048, N=3072, K=2048)
  gemm_bt_k<<<dim3(3072 / 128, 2048 / 128), 256, 0, stream>>>(Xbf, WqkvT, qkv,
                                                              2048, 3072, 2048);
  rope_cvt_k<<<dim3(5, S_LEN), 256, 0, stream>>>(qkv, cosb, sinb, Qbf, Kbf);
  vtrans_k<<<dim3(S_LEN / 64, NG), 256, 0, stream>>>(qkv, Vt);

  attn5_k<<<dim3(NG * NHQ, 8), 512, 0, stream>>>(Qbf, Kbf, Vt, attnO);

  // out = attnO @ Wd  (M=2048, N=2048, K=2048)
  gemm_bt_k<<<dim3(2048 / 128, 2048 / 128), 256, 0, stream>>>(attnO, WdT, out,
                                                              2048, 2048, 2048);
}

// Round 9
// 177.100 us; speedup vs baseline: 1.3349x; 1.0925x over previous
//
#include <hip/hip_runtime.h>

#define S_LEN 2048
#define HID_DIM 2048
#define NG 8
#define NHQ 4
#define DH 64
#define QKV_N 3072   // G*(HQ+2)*D
#define ATT_SCALE 0.125f

typedef short short8 __attribute__((ext_vector_type(8)));
typedef float f32x4 __attribute__((ext_vector_type(4)));
typedef unsigned short ushort_t;

__device__ __forceinline__ unsigned short f2bf(float f) {
  unsigned u = __builtin_bit_cast(unsigned, f);
  u += 0x7fffu + ((u >> 16) & 1u);   // RNE
  return (unsigned short)(u >> 16);
}

__device__ __forceinline__ void mfma16(f32x4& d, short8 a, short8 b) {
  asm volatile("v_mfma_f32_16x16x32_bf16 %0, %1, %2, %0" : "+v"(d) : "v"(a), "v"(b));
}

#define GLDS16(gp, lp) __builtin_amdgcn_global_load_lds( \
    (__attribute__((address_space(1))) void*)(gp),       \
    (__attribute__((address_space(3))) void*)(lp), 16, 0, 0)

// ---------------- fp32 -> bf16 convert (vectorized) ----------------
__global__ __launch_bounds__(256) void cvt_bf16_k(const float* __restrict__ in,
                                                  ushort_t* __restrict__ out, int n4) {
  int i = blockIdx.x * 256 + threadIdx.x;
  if (i >= n4) return;
  float4 v = ((const float4*)in)[i];
  ushort4 o;
  o.x = f2bf(v.x); o.y = f2bf(v.y); o.z = f2bf(v.z); o.w = f2bf(v.w);
  ((ushort4*)out)[i] = o;
}

// ---------------- fp32 -> bf16 transpose: out[C][R] = in[R][C]^T ----------------
__global__ __launch_bounds__(256) void tcvt_k(const float* __restrict__ in,
                                              ushort_t* __restrict__ out, int R, int C) {
  __shared__ ushort_t t[32][33];
  int bx = blockIdx.x * 32, by = blockIdx.y * 32;
  int tx = threadIdx.x & 31, ty = threadIdx.x >> 5;
  for (int j = ty; j < 32; j += 8)
    t[j][tx] = f2bf(in[(long)(by + j) * C + bx + tx]);
  __syncthreads();
  for (int j = ty; j < 32; j += 8)
    out[(long)(bx + j) * R + by + tx] = t[tx][j];
}

// ---------------- bf16 MFMA GEMM (round-5-verified single-buffer m97 form) ----
__global__ __launch_bounds__(256) void gemm_bt_k(const ushort_t* __restrict__ A,
                                                 const ushort_t* __restrict__ BT,
                                                 float* __restrict__ C,
                                                 int M, int N, int K) {
  __shared__ __align__(16) ushort_t Al[128 * 32];
  __shared__ __align__(16) ushort_t Bl[128 * 32];
  const int tid = threadIdx.x;
  const int w = tid >> 6, lane = tid & 63;
  const int m0 = blockIdx.y * 128, n0 = blockIdx.x * 128;

  const int srow = lane >> 2;
  const int skk = (lane & 3) << 3;
  const ushort_t* Ag = A + (long)(m0 + 32 * w + srow) * K + skk;
  const ushort_t* Bg = BT + (long)(n0 + 32 * w + srow) * K + skk;
  ushort_t* Als = &Al[(32 * w) * 32];
  ushort_t* Bls = &Bl[(32 * w) * 32];

  f32x4 acc[4][4];
#pragma unroll
  for (int i = 0; i < 4; ++i)
#pragma unroll
    for (int j = 0; j < 4; ++j) acc[i][j] = (f32x4){0.f, 0.f, 0.f, 0.f};

  const int fr = lane & 15;
  const int kq = (lane >> 4) << 3;
  const int wm = w >> 1, wn = w & 1;

  for (int kt = 0; kt < K; kt += 32) {
    GLDS16(Ag, Als);
    GLDS16(Ag + 16 * K, Als + 16 * 32);
    GLDS16(Bg, Bls);
    GLDS16(Bg + 16 * K, Bls + 16 * 32);
    Ag += 32; Bg += 32;
    __syncthreads();
    short8 af[4], bfr[4];
#pragma unroll
    for (int mf = 0; mf < 4; ++mf)
      af[mf] = *(const short8*)&Al[(64 * wm + 16 * mf + fr) * 32 + kq];
#pragma unroll
    for (int nf = 0; nf < 4; ++nf)
      bfr[nf] = *(const short8*)&Bl[(64 * wn + 16 * nf + fr) * 32 + kq];
#pragma unroll
    for (int mf = 0; mf < 4; ++mf)
#pragma unroll
      for (int nf = 0; nf < 4; ++nf)
        mfma16(acc[mf][nf], af[mf], bfr[nf]);
    __syncthreads();
  }

  const int crow = m0 + 64 * wm + 4 * (lane >> 4);
  const int ccol = n0 + 64 * wn + fr;
#pragma unroll
  for (int mf = 0; mf < 4; ++mf)
#pragma unroll
    for (int nf = 0; nf < 4; ++nf)
#pragma unroll
      for (int r = 0; r < 4; ++r)
        C[(long)(crow + 16 * mf + r) * N + ccol + 16 * nf] = acc[mf][nf][r];
}

// ---------------- fused RoPE + bf16 convert, head-major layouts ----------------
__global__ __launch_bounds__(256) void rope_cvt_k(const float* __restrict__ qkv,
                                                  const float* __restrict__ cosb,
                                                  const float* __restrict__ sinb,
                                                  ushort_t* __restrict__ Qbf,
                                                  ushort_t* __restrict__ Kbf) {
  int p = blockIdx.x * 256 + threadIdx.x;  // 0..1279
  int s = blockIdx.y;
  int i = p & 31;
  int hh = p >> 5;                         // 0..39
  int g = hh / 5, h = hh % 5;              // h: q0..q3, k
  const float* base = qkv + (long)s * QKV_N + g * 384 + h * 64;
  float c = cosb[s * 32 + i], sn = sinb[s * 32 + i];
  float x1 = base[i], x2 = base[i + 32];
  float y1 = x1 * c - x2 * sn;
  float y2 = x2 * c + x1 * sn;
  if (h < 4) {
    ushort_t* dst = Qbf + ((long)(g * 4 + h) * 2048 + s) * 64;
    dst[i] = f2bf(y1 * ATT_SCALE);
    dst[i + 32] = f2bf(y2 * ATT_SCALE);
  } else {
    ushort_t* dst = Kbf + ((long)g * 2048 + s) * 64;
    dst[i] = f2bf(y1);
    dst[i + 32] = f2bf(y2);
  }
}

// ---------------- V transpose to bf16: Vt[g][d][s] ----------------
__global__ __launch_bounds__(256) void vtrans_k(const float* __restrict__ qkv,
                                                ushort_t* __restrict__ Vt) {
  __shared__ ushort_t t[64][65];
  int s0 = blockIdx.x * 64, g = blockIdx.y;
  for (int idx = threadIdx.x; idx < 4096; idx += 256) {
    int r = idx >> 6, d = idx & 63;
    t[d][r] = f2bf(qkv[(long)(s0 + r) * QKV_N + g * 384 + 320 + d]);
  }
  __syncthreads();
  for (int idx = threadIdx.x; idx < 4096; idx += 256) {
    int d = idx >> 6, c = idx & 63;
    Vt[((long)g * 64 + d) * 2048 + s0 + c] = t[d][c];
  }
}

// ---------------- bf16 MFMA flash attention v8 ----------------
// attn5 data path (verified) with two changes:
//  (1) lsum via ones-column MFMA (mfma16(os, pa, ones)) -> removes the
//      16-shuffle sum reduction per tile-step.
//  (2) 4-wave / 256-thr blocks over 64 q-rows; grid 32x32 = 1024 blocks,
//      LDS 40KB -> up to 4 blocks/CU (16 waves/CU), residency-balanced
//      u-mapping {31-b, 16+b, 15-b, b} (each CU quadruple = 66 steps).
__global__ __launch_bounds__(256, 4) void attn8_k(const ushort_t* __restrict__ Qbf,
                                                  const ushort_t* __restrict__ Kbf,
                                                  const ushort_t* __restrict__ Vt,
                                                  ushort_t* __restrict__ outb) {
  __shared__ __align__(16) ushort_t Kl[2][64 * 64];
  __shared__ __align__(16) ushort_t Vl[2][64 * 64];
  __shared__ __align__(16) ushort_t Pl[4][1024];
  const int gh = blockIdx.x;
  const int y = blockIdx.y;
  const int bb = y & 7, aa = y >> 3;
  const int u = (aa == 0) ? 31 - bb : (aa == 1) ? 16 + bb : (aa == 2) ? 15 - bb : bb;
  const int g = gh >> 2;
  const int w = threadIdx.x >> 6, l = threadIdx.x & 63;
  const int li = l & 15, hi = l >> 4;
  const int q0 = 64 * u + 16 * w;
  const int nt = u + 1;

  const ushort_t* Qh = Qbf + (long)gh * 2048 * 64;
  const ushort_t* Kh = Kbf + (long)g * 2048 * 64;
  const ushort_t* Vh = Vt + (long)g * 64 * 2048;
  char* Pw = (char*)&Pl[w][0];

  // staging: wave w covers rows [16w,16w+16) as two 8-row GLDS units.
  // lane l: row sr = 16w + (l>>3) (and sr+8), global chunk sc = (l&7)^(l>>3)
  // (LDS dest linear; (sr&7) == (l>>3) for both units).
  const int sr = 16 * w + (l >> 3);
  const int sc = (l & 7) ^ (l >> 3);
  const short8 ones = {0x3F80, 0x3F80, 0x3F80, 0x3F80, 0x3F80, 0x3F80, 0x3F80, 0x3F80};

  short8 aq0 = *(const short8*)&Qh[(q0 + li) * 64 + hi * 8];
  short8 aq1 = *(const short8*)&Qh[(q0 + li) * 64 + 32 + hi * 8];

  f32x4 o[4];
#pragma unroll
  for (int df = 0; df < 4; ++df) o[df] = (f32x4){0.f, 0.f, 0.f, 0.f};
  f32x4 os = (f32x4){0.f, 0.f, 0.f, 0.f};   // row-sums via ones-column MFMA
  float m[4] = {-1e30f, -1e30f, -1e30f, -1e30f};

  // prologue: stage tile 0 into buf 0
  GLDS16(Kh + (long)sr * 64 + sc * 8,         &Kl[0][(16 * w) * 64]);
  GLDS16(Kh + (long)(sr + 8) * 64 + sc * 8,   &Kl[0][(16 * w + 8) * 64]);
  GLDS16(Vh + (long)sr * 2048 + sc * 8,       &Vl[0][(16 * w) * 64]);
  GLDS16(Vh + (long)(sr + 8) * 2048 + sc * 8, &Vl[0][(16 * w + 8) * 64]);
  __syncthreads();

  int buf = 0;
  for (int it = 0; it < nt; ++it) {
    const int t0 = it * 64;
    if (it + 1 < nt) {  // prefetch next tile into buf^1 (stays in flight)
      const int tn = t0 + 64;
      GLDS16(Kh + (long)(tn + sr) * 64 + sc * 8,       &Kl[buf ^ 1][(16 * w) * 64]);
      GLDS16(Kh + (long)(tn + sr + 8) * 64 + sc * 8,   &Kl[buf ^ 1][(16 * w + 8) * 64]);
      GLDS16(Vh + (long)sr * 2048 + tn + sc * 8,       &Vl[buf ^ 1][(16 * w) * 64]);
      GLDS16(Vh + (long)(sr + 8) * 2048 + tn + sc * 8, &Vl[buf ^ 1][(16 * w + 8) * 64]);
    }
    const ushort_t* kb = &Kl[buf][0];
    const ushort_t* vb = &Vl[buf][0];

    // ---- QK^T: S[16q][64t] ----
    f32x4 sf[4];
#pragma unroll
    for (int f = 0; f < 4; ++f) sf[f] = (f32x4){0.f, 0.f, 0.f, 0.f};
    __builtin_amdgcn_s_setprio(1);
#pragma unroll
    for (int f = 0; f < 4; ++f) {
      const int row = 16 * f + li;
      short8 b0 = *(const short8*)&kb[row * 64 + ((hi ^ (row & 7)) << 3)];
      short8 b1 = *(const short8*)&kb[row * 64 + (((hi + 4) ^ (row & 7)) << 3)];
      mfma16(sf[f], aq0, b0);
      mfma16(sf[f], aq1, b1);
    }
    __builtin_amdgcn_s_setprio(0);

    // ---- causal mask (diagonal tile only) ----
    if (t0 + 63 > q0) {
#pragma unroll
      for (int f = 0; f < 4; ++f) {
        int t = t0 + 16 * f + li;
#pragma unroll
        for (int r = 0; r < 4; ++r)
          if (t > q0 + 4 * hi + r) sf[f][r] = -1e30f;
      }
    }
    // ---- online softmax (max-reduce only; sum comes from ones-MFMA) ----
    float pm[4], mn[4], corr[4];
#pragma unroll
    for (int r = 0; r < 4; ++r)
      pm[r] = fmaxf(fmaxf(sf[0][r], sf[1][r]), fmaxf(sf[2][r], sf[3][r]));
#pragma unroll
    for (int dlt = 1; dlt < 16; dlt <<= 1)
#pragma unroll
      for (int r = 0; r < 4; ++r) pm[r] = fmaxf(pm[r], __shfl_xor(pm[r], dlt, 64));
#pragma unroll
    for (int r = 0; r < 4; ++r) {
      mn[r] = fmaxf(m[r], pm[r]);
      corr[r] = __expf(m[r] - mn[r]);
      m[r] = mn[r];
    }
#pragma unroll
    for (int f = 0; f < 4; ++f) {
      int k2 = 2 * (li + 16 * f);
#pragma unroll
      for (int r = 0; r < 4; ++r) {
        float p = __expf(sf[f][r] - mn[r]);
        int q = 4 * hi + r;
        *(ushort_t*)(Pw + q * 128 + (k2 ^ ((q & 7) << 4))) = f2bf(p);
      }
    }
#pragma unroll
    for (int df = 0; df < 4; ++df)
#pragma unroll
      for (int r = 0; r < 4; ++r) o[df][r] *= corr[r];
#pragma unroll
    for (int r = 0; r < 4; ++r) os[r] *= corr[r];

    // ---- PV: O[16q][64d] += P * V^T; row-sums accumulate via ones-frag ----
    __builtin_amdgcn_s_setprio(1);
#pragma unroll
    for (int kst = 0; kst < 2; ++kst) {
      short8 pa = *(const short8*)(Pw + li * 128 + (((4 * kst + hi) ^ (li & 7)) << 4));
#pragma unroll
      for (int df = 0; df < 4; ++df) {
        const int row = 16 * df + li;
        short8 bv = *(const short8*)&vb[row * 64 + (((4 * kst + hi) ^ (row & 7)) << 3)];
        mfma16(o[df], pa, bv);
      }
      mfma16(os, pa, ones);
    }
    __builtin_amdgcn_s_setprio(0);

    __syncthreads();  // drains GLDS (vmcnt) + all waves done reading buf
    buf ^= 1;
  }
  // ---- epilogue: normalize by ones-MFMA row-sums, store bf16 ----
#pragma unroll
  for (int r = 0; r < 4; ++r) {
    float inv = 1.f / os[r];
#pragma unroll
    for (int df = 0; df < 4; ++df)
      outb[(long)(q0 + 4 * hi + r) * HID_DIM + gh * 64 + 16 * df + li] =
          f2bf(o[df][r] * inv);
  }
}

extern "C" void kernel_launch(void* const* d_in, const int* in_sizes, int n_in,
                              void* d_out, int out_size, void* d_ws, size_t ws_size,
                              hipStream_t stream) {
  const float* X    = (const float*)d_in[0];  // 2048x2048
  const float* cosb = (const float*)d_in[1];  // 2048x32
  const float* sinb = (const float*)d_in[2];  // 2048x32
  const float* Wqkv = (const float*)d_in[3];  // 2048x3072
  const float* Wd   = (const float*)d_in[4];  // 2048x2048
  float* out = (float*)d_out;                 // 2048x2048 fp32

  char* ws = (char*)d_ws;
  ushort_t* Xbf   = (ushort_t*)ws;
  ushort_t* WqkvT = Xbf + (size_t)2048 * 2048;
  ushort_t* WdT   = WqkvT + (size_t)3072 * 2048;
  float*    qkv   = (float*)(WdT + (size_t)2048 * 2048);
  ushort_t* Qbf   = Xbf;
  ushort_t* Kbf   = WqkvT;
  ushort_t* Vt    = WqkvT + (size_t)NG * 2048 * 64;
  ushort_t* attnO = (ushort_t*)qkv;

  cvt_bf16_k<<<4096, 256, 0, stream>>>(X, Xbf, (2048 * 2048) / 4);
  tcvt_k<<<dim3(3072 / 32, 2048 / 32), 256, 0, stream>>>(Wqkv, WqkvT, 2048, 3072);
  tcvt_k<<<dim3(2048 / 32, 2048 / 32), 256, 0, stream>>>(Wd, WdT, 2048, 2048);

  // qkv = X @ Wqkv  (M=2048, N=3072, K=2048)
  gemm_bt_k<<<dim3(3072 / 128, 2048 / 128), 256, 0, stream>>>(Xbf, WqkvT, qkv,
                                                              2048, 3072, 2048);
  rope_cvt_k<<<dim3(5, S_LEN), 256, 0, stream>>>(qkv, cosb, sinb, Qbf, Kbf);
  vtrans_k<<<dim3(S_LEN / 64, NG), 256, 0, stream>>>(qkv, Vt);

  attn8_k<<<dim3(NG * NHQ, 32), 256, 0, stream>>>(Qbf, Kbf, Vt, attnO);

  // out = attnO @ Wd  (M=2048, N=2048, K=2048)
  gemm_bt_k<<<dim3(2048 / 128, 2048 / 128), 256, 0, stream>>>(attnO, WdT, out,
                                                              2048, 2048, 2048);
}

// Round 10
// 161.750 us; speedup vs baseline: 1.4615x; 1.0949x over previous
//
#include <hip/hip_runtime.h>

#define S_LEN 2048
#define HID_DIM 2048
#define NG 8
#define NHQ 4
#define DH 64
#define QKV_N 3072   // G*(HQ+2)*D
// Q pre-scale = ATT_SCALE * log2(e): softmax runs in exp2 domain
#define QSCALE 0.18033688011112042f
#define FIXMAX 12.0f

typedef short short8 __attribute__((ext_vector_type(8)));
typedef float f32x4 __attribute__((ext_vector_type(4)));
typedef unsigned short ushort_t;

__device__ __forceinline__ unsigned short f2bf(float f) {
  unsigned u = __builtin_bit_cast(unsigned, f);
  u += 0x7fffu + ((u >> 16) & 1u);   // RNE
  return (unsigned short)(u >> 16);
}

__device__ __forceinline__ void mfma16(f32x4& d, short8 a, short8 b) {
  asm volatile("v_mfma_f32_16x16x32_bf16 %0, %1, %2, %0" : "+v"(d) : "v"(a), "v"(b));
}

#define GLDS16(gp, lp) __builtin_amdgcn_global_load_lds( \
    (__attribute__((address_space(1))) void*)(gp),       \
    (__attribute__((address_space(3))) void*)(lp), 16, 0, 0)

// ---------------- fp32 -> bf16 convert (vectorized) ----------------
__global__ __launch_bounds__(256) void cvt_bf16_k(const float* __restrict__ in,
                                                  ushort_t* __restrict__ out, int n4) {
  int i = blockIdx.x * 256 + threadIdx.x;
  if (i >= n4) return;
  float4 v = ((const float4*)in)[i];
  ushort4 o;
  o.x = f2bf(v.x); o.y = f2bf(v.y); o.z = f2bf(v.z); o.w = f2bf(v.w);
  ((ushort4*)out)[i] = o;
}

// ---------------- fp32 -> bf16 transpose: out[C][R] = in[R][C]^T ----------------
__global__ __launch_bounds__(256) void tcvt_k(const float* __restrict__ in,
                                              ushort_t* __restrict__ out, int R, int C) {
  __shared__ ushort_t t[32][33];
  int bx = blockIdx.x * 32, by = blockIdx.y * 32;
  int tx = threadIdx.x & 31, ty = threadIdx.x >> 5;
  for (int j = ty; j < 32; j += 8)
    t[j][tx] = f2bf(in[(long)(by + j) * C + bx + tx]);
  __syncthreads();
  for (int j = ty; j < 32; j += 8)
    out[(long)(bx + j) * R + by + tx] = t[tx][j];
}

// ---------------- bf16 MFMA GEMM (round-5-verified single-buffer m97 form) ----
__global__ __launch_bounds__(256) void gemm_bt_k(const ushort_t* __restrict__ A,
                                                 const ushort_t* __restrict__ BT,
                                                 float* __restrict__ C,
                                                 int M, int N, int K) {
  __shared__ __align__(16) ushort_t Al[128 * 32];
  __shared__ __align__(16) ushort_t Bl[128 * 32];
  const int tid = threadIdx.x;
  const int w = tid >> 6, lane = tid & 63;
  const int m0 = blockIdx.y * 128, n0 = blockIdx.x * 128;

  const int srow = lane >> 2;
  const int skk = (lane & 3) << 3;
  const ushort_t* Ag = A + (long)(m0 + 32 * w + srow) * K + skk;
  const ushort_t* Bg = BT + (long)(n0 + 32 * w + srow) * K + skk;
  ushort_t* Als = &Al[(32 * w) * 32];
  ushort_t* Bls = &Bl[(32 * w) * 32];

  f32x4 acc[4][4];
#pragma unroll
  for (int i = 0; i < 4; ++i)
#pragma unroll
    for (int j = 0; j < 4; ++j) acc[i][j] = (f32x4){0.f, 0.f, 0.f, 0.f};

  const int fr = lane & 15;
  const int kq = (lane >> 4) << 3;
  const int wm = w >> 1, wn = w & 1;

  for (int kt = 0; kt < K; kt += 32) {
    GLDS16(Ag, Als);
    GLDS16(Ag + 16 * K, Als + 16 * 32);
    GLDS16(Bg, Bls);
    GLDS16(Bg + 16 * K, Bls + 16 * 32);
    Ag += 32; Bg += 32;
    __syncthreads();
    short8 af[4], bfr[4];
#pragma unroll
    for (int mf = 0; mf < 4; ++mf)
      af[mf] = *(const short8*)&Al[(64 * wm + 16 * mf + fr) * 32 + kq];
#pragma unroll
    for (int nf = 0; nf < 4; ++nf)
      bfr[nf] = *(const short8*)&Bl[(64 * wn + 16 * nf + fr) * 32 + kq];
#pragma unroll
    for (int mf = 0; mf < 4; ++mf)
#pragma unroll
      for (int nf = 0; nf < 4; ++nf)
        mfma16(acc[mf][nf], af[mf], bfr[nf]);
    __syncthreads();
  }

  const int crow = m0 + 64 * wm + 4 * (lane >> 4);
  const int ccol = n0 + 64 * wn + fr;
#pragma unroll
  for (int mf = 0; mf < 4; ++mf)
#pragma unroll
    for (int nf = 0; nf < 4; ++nf)
#pragma unroll
      for (int r = 0; r < 4; ++r)
        C[(long)(crow + 16 * mf + r) * N + ccol + 16 * nf] = acc[mf][nf][r];
}

// ---------------- fused RoPE + bf16 convert, head-major layouts ----------------
// Q scaled by ATT_SCALE*log2(e)  ->  softmax runs in exp2 domain.
__global__ __launch_bounds__(256) void rope_cvt_k(const float* __restrict__ qkv,
                                                  const float* __restrict__ cosb,
                                                  const float* __restrict__ sinb,
                                                  ushort_t* __restrict__ Qbf,
                                                  ushort_t* __restrict__ Kbf) {
  int p = blockIdx.x * 256 + threadIdx.x;  // 0..1279
  int s = blockIdx.y;
  int i = p & 31;
  int hh = p >> 5;                         // 0..39
  int g = hh / 5, h = hh % 5;              // h: q0..q3, k
  const float* base = qkv + (long)s * QKV_N + g * 384 + h * 64;
  float c = cosb[s * 32 + i], sn = sinb[s * 32 + i];
  float x1 = base[i], x2 = base[i + 32];
  float y1 = x1 * c - x2 * sn;
  float y2 = x2 * c + x1 * sn;
  if (h < 4) {
    ushort_t* dst = Qbf + ((long)(g * 4 + h) * 2048 + s) * 64;
    dst[i] = f2bf(y1 * QSCALE);
    dst[i + 32] = f2bf(y2 * QSCALE);
  } else {
    ushort_t* dst = Kbf + ((long)g * 2048 + s) * 64;
    dst[i] = f2bf(y1);
    dst[i + 32] = f2bf(y2);
  }
}

// ---------------- V transpose to bf16: Vt[g][d][s] ----------------
__global__ __launch_bounds__(256) void vtrans_k(const float* __restrict__ qkv,
                                                ushort_t* __restrict__ Vt) {
  __shared__ ushort_t t[64][65];
  int s0 = blockIdx.x * 64, g = blockIdx.y;
  for (int idx = threadIdx.x; idx < 4096; idx += 256) {
    int r = idx >> 6, d = idx & 63;
    t[d][r] = f2bf(qkv[(long)(s0 + r) * QKV_N + g * 384 + 320 + d]);
  }
  __syncthreads();
  for (int idx = threadIdx.x; idx < 4096; idx += 256) {
    int d = idx >> 6, c = idx & 63;
    Vt[((long)g * 64 + d) * 2048 + s0 + c] = t[d][c];
  }
}

// ---------------- bf16 MFMA flash attention v9: fixed-max softmax ----------------
// attn8 data path (verified) minus the online-max machinery:
//  P[q][t] = exp2(S'[q][t] - 12)  (S' already in log2 domain via QSCALE).
//  Exact after normalization: lsum (ones-MFMA) sums the SAME bf16 P as PV,
//  so scale & truncation bias cancel in O/lsum. No max-reduce shuffles, no
//  corr/rescale, no m-state. Masked S = -1e30 -> exp2 underflows to 0.
__global__ __launch_bounds__(256, 4) void attn9_k(const ushort_t* __restrict__ Qbf,
                                                  const ushort_t* __restrict__ Kbf,
                                                  const ushort_t* __restrict__ Vt,
                                                  ushort_t* __restrict__ outb) {
  __shared__ __align__(16) ushort_t Kl[2][64 * 64];
  __shared__ __align__(16) ushort_t Vl[2][64 * 64];
  __shared__ __align__(16) ushort_t Pl[4][1024];
  const int gh = blockIdx.x;
  const int y = blockIdx.y;
  const int bb = y & 7, aa = y >> 3;
  const int u = (aa == 0) ? 31 - bb : (aa == 1) ? 16 + bb : (aa == 2) ? 15 - bb : bb;
  const int g = gh >> 2;
  const int w = threadIdx.x >> 6, l = threadIdx.x & 63;
  const int li = l & 15, hi = l >> 4;
  const int q0 = 64 * u + 16 * w;
  const int nt = u + 1;

  const ushort_t* Qh = Qbf + (long)gh * 2048 * 64;
  const ushort_t* Kh = Kbf + (long)g * 2048 * 64;
  const ushort_t* Vh = Vt + (long)g * 64 * 2048;
  char* Pw = (char*)&Pl[w][0];

  const int sr = 16 * w + (l >> 3);
  const int sc = (l & 7) ^ (l >> 3);
  const short8 ones = {0x3F80, 0x3F80, 0x3F80, 0x3F80, 0x3F80, 0x3F80, 0x3F80, 0x3F80};

  short8 aq0 = *(const short8*)&Qh[(q0 + li) * 64 + hi * 8];
  short8 aq1 = *(const short8*)&Qh[(q0 + li) * 64 + 32 + hi * 8];

  f32x4 o[4];
#pragma unroll
  for (int df = 0; df < 4; ++df) o[df] = (f32x4){0.f, 0.f, 0.f, 0.f};
  f32x4 os = (f32x4){0.f, 0.f, 0.f, 0.f};   // row-sums via ones-column MFMA

  // prologue: stage tile 0 into buf 0
  GLDS16(Kh + (long)sr * 64 + sc * 8,         &Kl[0][(16 * w) * 64]);
  GLDS16(Kh + (long)(sr + 8) * 64 + sc * 8,   &Kl[0][(16 * w + 8) * 64]);
  GLDS16(Vh + (long)sr * 2048 + sc * 8,       &Vl[0][(16 * w) * 64]);
  GLDS16(Vh + (long)(sr + 8) * 2048 + sc * 8, &Vl[0][(16 * w + 8) * 64]);
  __syncthreads();

  int buf = 0;
  for (int it = 0; it < nt; ++it) {
    const int t0 = it * 64;
    if (it + 1 < nt) {  // prefetch next tile into buf^1 (stays in flight)
      const int tn = t0 + 64;
      GLDS16(Kh + (long)(tn + sr) * 64 + sc * 8,       &Kl[buf ^ 1][(16 * w) * 64]);
      GLDS16(Kh + (long)(tn + sr + 8) * 64 + sc * 8,   &Kl[buf ^ 1][(16 * w + 8) * 64]);
      GLDS16(Vh + (long)sr * 2048 + tn + sc * 8,       &Vl[buf ^ 1][(16 * w) * 64]);
      GLDS16(Vh + (long)(sr + 8) * 2048 + tn + sc * 8, &Vl[buf ^ 1][(16 * w + 8) * 64]);
    }
    const ushort_t* kb = &Kl[buf][0];
    const ushort_t* vb = &Vl[buf][0];

    // ---- QK^T: S'[16q][64t] (log2 domain) ----
    f32x4 sf[4];
#pragma unroll
    for (int f = 0; f < 4; ++f) sf[f] = (f32x4){0.f, 0.f, 0.f, 0.f};
    __builtin_amdgcn_s_setprio(1);
#pragma unroll
    for (int f = 0; f < 4; ++f) {
      const int row = 16 * f + li;
      short8 b0 = *(const short8*)&kb[row * 64 + ((hi ^ (row & 7)) << 3)];
      short8 b1 = *(const short8*)&kb[row * 64 + (((hi + 4) ^ (row & 7)) << 3)];
      mfma16(sf[f], aq0, b0);
      mfma16(sf[f], aq1, b1);
    }
    __builtin_amdgcn_s_setprio(0);

    // ---- causal mask (diagonal tile only) ----
    if (t0 + 63 > q0) {
#pragma unroll
      for (int f = 0; f < 4; ++f) {
        int t = t0 + 16 * f + li;
#pragma unroll
        for (int r = 0; r < 4; ++r)
          if (t > q0 + 4 * hi + r) sf[f][r] = -1e30f;
      }
    }
    // ---- fixed-max softmax: P = exp2(S' - 12), truncate-store to bf16 ----
#pragma unroll
    for (int f = 0; f < 4; ++f) {
      int k2 = 2 * (li + 16 * f);
#pragma unroll
      for (int r = 0; r < 4; ++r) {
        float p = __builtin_amdgcn_exp2f(sf[f][r] - FIXMAX);
        int q = 4 * hi + r;
        *(ushort_t*)(Pw + q * 128 + (k2 ^ ((q & 7) << 4))) =
            (ushort_t)(__builtin_bit_cast(unsigned, p) >> 16);
      }
    }

    // ---- PV: O[16q][64d] += P * V^T; row-sums accumulate via ones-frag ----
    __builtin_amdgcn_s_setprio(1);
#pragma unroll
    for (int kst = 0; kst < 2; ++kst) {
      short8 pa = *(const short8*)(Pw + li * 128 + (((4 * kst + hi) ^ (li & 7)) << 4));
#pragma unroll
      for (int df = 0; df < 4; ++df) {
        const int row = 16 * df + li;
        short8 bv = *(const short8*)&vb[row * 64 + (((4 * kst + hi) ^ (row & 7)) << 3)];
        mfma16(o[df], pa, bv);
      }
      mfma16(os, pa, ones);
    }
    __builtin_amdgcn_s_setprio(0);

    __syncthreads();  // drains GLDS (vmcnt) + all waves done reading buf
    buf ^= 1;
  }
  // ---- epilogue: normalize by ones-MFMA row-sums, store bf16 (RNE) ----
#pragma unroll
  for (int r = 0; r < 4; ++r) {
    float inv = 1.f / os[r];
#pragma unroll
    for (int df = 0; df < 4; ++df)
      outb[(long)(q0 + 4 * hi + r) * HID_DIM + gh * 64 + 16 * df + li] =
          f2bf(o[df][r] * inv);
  }
}

extern "C" void kernel_launch(void* const* d_in, const int* in_sizes, int n_in,
                              void* d_out, int out_size, void* d_ws, size_t ws_size,
                              hipStream_t stream) {
  const float* X    = (const float*)d_in[0];  // 2048x2048
  const float* cosb = (const float*)d_in[1];  // 2048x32
  const float* sinb = (const float*)d_in[2];  // 2048x32
  const float* Wqkv = (const float*)d_in[3];  // 2048x3072
  const float* Wd   = (const float*)d_in[4];  // 2048x2048
  float* out = (float*)d_out;                 // 2048x2048 fp32

  char* ws = (char*)d_ws;
  ushort_t* Xbf   = (ushort_t*)ws;
  ushort_t* WqkvT = Xbf + (size_t)2048 * 2048;
  ushort_t* WdT   = WqkvT + (size_t)3072 * 2048;
  float*    qkv   = (float*)(WdT + (size_t)2048 * 2048);
  ushort_t* Qbf   = Xbf;
  ushort_t* Kbf   = WqkvT;
  ushort_t* Vt    = WqkvT + (size_t)NG * 2048 * 64;
  ushort_t* attnO = (ushort_t*)qkv;

  cvt_bf16_k<<<4096, 256, 0, stream>>>(X, Xbf, (2048 * 2048) / 4);
  tcvt_k<<<dim3(3072 / 32, 2048 / 32), 256, 0, stream>>>(Wqkv, WqkvT, 2048, 3072);
  tcvt_k<<<dim3(2048 / 32, 2048 / 32), 256, 0, stream>>>(Wd, WdT, 2048, 2048);

  // qkv = X @ Wqkv  (M=2048, N=3072, K=2048)
  gemm_bt_k<<<dim3(3072 / 128, 2048 / 128), 256, 0, stream>>>(Xbf, WqkvT, qkv,
                                                              2048, 3072, 2048);
  rope_cvt_k<<<dim3(5, S_LEN), 256, 0, stream>>>(qkv, cosb, sinb, Qbf, Kbf);
  vtrans_k<<<dim3(S_LEN / 64, NG), 256, 0, stream>>>(qkv, Vt);

  attn9_k<<<dim3(NG * NHQ, 32), 256, 0, stream>>>(Qbf, Kbf, Vt, attnO);

  // out = attnO @ Wd  (M=2048, N=2048, K=2048)
  gemm_bt_k<<<dim3(2048 / 128, 2048 / 128), 256, 0, stream>>>(attnO, WdT, out,
                                                              2048, 2048, 2048);
}

// Round 11
// 145.242 us; speedup vs baseline: 1.6276x; 1.1137x over previous
//
#include <hip/hip_runtime.h>

#define S_LEN 2048
#define HID_DIM 2048
#define NG 8
#define NHQ 4
#define DH 64
// Q pre-scale = ATT_SCALE * log2(e): softmax runs in exp2 domain
#define QSCALE 0.18033688011112042f
#define FIXMAX 12.0f

typedef short short8 __attribute__((ext_vector_type(8)));
typedef float f32x4 __attribute__((ext_vector_type(4)));
typedef unsigned short ushort_t;

__device__ __forceinline__ unsigned short f2bf(float f) {
  unsigned u = __builtin_bit_cast(unsigned, f);
  u += 0x7fffu + ((u >> 16) & 1u);   // RNE
  return (unsigned short)(u >> 16);
}

__device__ __forceinline__ void mfma16(f32x4& d, short8 a, short8 b) {
  asm volatile("v_mfma_f32_16x16x32_bf16 %0, %1, %2, %0" : "+v"(d) : "v"(a), "v"(b));
}

#define GLDS16(gp, lp) __builtin_amdgcn_global_load_lds( \
    (__attribute__((address_space(1))) void*)(gp),       \
    (__attribute__((address_space(3))) void*)(lp), 16, 0, 0)

// ---------------- fp32 -> bf16 convert (vectorized) ----------------
__global__ __launch_bounds__(256) void cvt_bf16_k(const float* __restrict__ in,
                                                  ushort_t* __restrict__ out, int n4) {
  int i = blockIdx.x * 256 + threadIdx.x;
  if (i >= n4) return;
  float4 v = ((const float4*)in)[i];
  ushort4 o;
  o.x = f2bf(v.x); o.y = f2bf(v.y); o.z = f2bf(v.z); o.w = f2bf(v.w);
  ((ushort4*)out)[i] = o;
}

// ---------------- fp32 -> bf16 transpose: out[C][R] = in[R][C]^T ----------------
__global__ __launch_bounds__(256) void tcvt_k(const float* __restrict__ in,
                                              ushort_t* __restrict__ out, int R, int C) {
  __shared__ ushort_t t[32][33];
  int bx = blockIdx.x * 32, by = blockIdx.y * 32;
  int tx = threadIdx.x & 31, ty = threadIdx.x >> 5;
  for (int j = ty; j < 32; j += 8)
    t[j][tx] = f2bf(in[(long)(by + j) * C + bx + tx]);
  __syncthreads();
  for (int j = ty; j < 32; j += 8)
    out[(long)(bx + j) * R + by + tx] = t[tx][j];
}

// ---------------- cos/sin transpose: csT[i][s] = cs[s][i]  (i<32) ----------------
__global__ __launch_bounds__(256) void cs_trans_k(const float* __restrict__ cosb,
                                                  const float* __restrict__ sinb,
                                                  float* __restrict__ cosT,
                                                  float* __restrict__ sinT) {
  int idx = blockIdx.x * 256 + threadIdx.x;   // 65536 total
  int s = idx >> 5, i = idx & 31;             // coalesced reads
  cosT[i * 2048 + s] = cosb[s * 32 + i];
  sinT[i * 2048 + s] = sinb[s * 32 + i];
}

// ======== shared GEMM K-loop pieces: 128x128 tile, BK=64, XOR-swizzled LDS ======
// Staging (per wave w, per operand): rows [32w,32w+32) as 4 GLDS units of 8 rows;
// lane l: row (l>>3) within unit, global 16B-chunk sc=(l&7)^(l>>3); LDS linear.
// ds_read: 16B chunk cidx=(lane>>4)+4c at byte row*128 + ((cidx^(row&7))<<4).
#define GEMM_PROLOG()                                                       \
  const int tid = threadIdx.x;                                              \
  const int w = tid >> 6, lane = tid & 63;                                  \
  const int m0 = blockIdx.y * 128, n0 = blockIdx.x * 128;                   \
  const int sl = lane >> 3;                                                 \
  const int sc = (lane & 7) ^ sl;                                           \
  const ushort_t* Ag = A + (size_t)(m0 + 32 * w + sl) * K + sc * 8;         \
  const ushort_t* Bg = BT + (size_t)(n0 + 32 * w + sl) * K + sc * 8;        \
  f32x4 acc[4][4];                                                          \
  _Pragma("unroll") for (int i = 0; i < 4; ++i)                             \
  _Pragma("unroll") for (int j = 0; j < 4; ++j)                             \
      acc[i][j] = (f32x4){0.f, 0.f, 0.f, 0.f};                              \
  const int fr = lane & 15;                                                 \
  const int kq4 = lane >> 4;                                                \
  const int wm = w >> 1, wn = w & 1;

#define GEMM_KLOOP()                                                        \
  for (int kt = 0; kt < K; kt += 64) {                                      \
    GLDS16(Ag,          &Al[(32 * w) * 64]);                                \
    GLDS16(Ag +  8 * K, &Al[(32 * w + 8) * 64]);                            \
    GLDS16(Ag + 16 * K, &Al[(32 * w + 16) * 64]);                           \
    GLDS16(Ag + 24 * K, &Al[(32 * w + 24) * 64]);                           \
    GLDS16(Bg,          &Bl[(32 * w) * 64]);                                \
    GLDS16(Bg +  8 * K, &Bl[(32 * w + 8) * 64]);                            \
    GLDS16(Bg + 16 * K, &Bl[(32 * w + 16) * 64]);                           \
    GLDS16(Bg + 24 * K, &Bl[(32 * w + 24) * 64]);                           \
    Ag += 64; Bg += 64;                                                     \
    __syncthreads();                                                        \
    _Pragma("unroll")                                                       \
    for (int c = 0; c < 2; ++c) {                                           \
      short8 af[4], bfr[4];                                                 \
      _Pragma("unroll") for (int mf = 0; mf < 4; ++mf) {                    \
        const int row = 64 * wm + 16 * mf + fr;                             \
        af[mf] = *(const short8*)&Al[row * 64 +                             \
                 (((kq4 + 4 * c) ^ (row & 7)) << 3)];                       \
      }                                                                     \
      _Pragma("unroll") for (int nf = 0; nf < 4; ++nf) {                    \
        const int row = 64 * wn + 16 * nf + fr;                             \
        bfr[nf] = *(const short8*)&Bl[row * 64 +                            \
                  (((kq4 + 4 * c) ^ (row & 7)) << 3)];                      \
      }                                                                     \
      _Pragma("unroll") for (int mf = 0; mf < 4; ++mf)                      \
      _Pragma("unroll") for (int nf = 0; nf < 4; ++nf)                      \
          mfma16(acc[mf][nf], af[mf], bfr[nf]);                             \
    }                                                                       \
    __syncthreads();                                                        \
  }

// ---------------- plain GEMM: C(MxN) fp32 = A(MxK) * BT(NxK)^T ----------------
__global__ __launch_bounds__(256) void gemm_bt_k(const ushort_t* __restrict__ A,
                                                 const ushort_t* __restrict__ BT,
                                                 float* __restrict__ C,
                                                 int M, int N, int K) {
  __shared__ __align__(16) ushort_t Al[128 * 64];
  __shared__ __align__(16) ushort_t Bl[128 * 64];
  GEMM_PROLOG();
  GEMM_KLOOP();
  const int crow = m0 + 64 * wm + 4 * (lane >> 4);
  const int ccol = n0 + 64 * wn + fr;
#pragma unroll
  for (int mf = 0; mf < 4; ++mf)
#pragma unroll
    for (int nf = 0; nf < 4; ++nf)
#pragma unroll
      for (int r = 0; r < 4; ++r)
        C[(size_t)(crow + 16 * mf + r) * N + ccol + 16 * nf] = acc[mf][nf][r];
}

// ---------- QKV GEMM with fused RoPE + bf16 + head-major epilogue ----------
// N=3072: each wave's 64-col span is exactly one head (wave-uniform branch).
// hb = ((n0%384)>>6)+wn in {0..3}=q, 4=k, 5=v; gg = n0/384.
// RoPE pair (d=i, d=i+32) lives in acc[mf][nf2] / acc[mf][nf2+2], same thread.
__global__ __launch_bounds__(256) void gemm_qkv_k(const ushort_t* __restrict__ A,
                                                  const ushort_t* __restrict__ BT,
                                                  const float* __restrict__ cosT,
                                                  const float* __restrict__ sinT,
                                                  ushort_t* __restrict__ Qbf,
                                                  ushort_t* __restrict__ Kbf,
                                                  ushort_t* __restrict__ Vbuf,
                                                  int M, int N, int K) {
  __shared__ __align__(16) ushort_t Al[128 * 64];
  __shared__ __align__(16) ushort_t Bl[128 * 64];
  GEMM_PROLOG();
  GEMM_KLOOP();
  const int crow = m0 + 64 * wm + 4 * (lane >> 4);
  const int hb = ((n0 % 384) >> 6) + wn;
  const int gg = n0 / 384;
  if (hb == 5) {  // v head: plain bf16, row-major [g][s][64]
    ushort_t* dst = Vbuf + (size_t)gg * 2048 * 64;
#pragma unroll
    for (int mf = 0; mf < 4; ++mf)
#pragma unroll
      for (int nf = 0; nf < 4; ++nf)
#pragma unroll
        for (int r = 0; r < 4; ++r)
          dst[(size_t)(crow + 16 * mf + r) * 64 + 16 * nf + fr] =
              f2bf(acc[mf][nf][r]);
  } else {        // q or k head: fused RoPE (+ QSCALE for q)
    const float qs = (hb < 4) ? QSCALE : 1.0f;
    ushort_t* dst = (hb < 4) ? Qbf + (size_t)(gg * 4 + hb) * 2048 * 64
                             : Kbf + (size_t)gg * 2048 * 64;
#pragma unroll
    for (int mf = 0; mf < 4; ++mf) {
#pragma unroll
      for (int nf2 = 0; nf2 < 2; ++nf2) {
        const int i = 16 * nf2 + fr;
        float4 cT = *(const float4*)&cosT[(size_t)i * 2048 + crow + 16 * mf];
        float4 sT = *(const float4*)&sinT[(size_t)i * 2048 + crow + 16 * mf];
        const float cc[4] = {cT.x, cT.y, cT.z, cT.w};
        const float ss[4] = {sT.x, sT.y, sT.z, sT.w};
#pragma unroll
        for (int r = 0; r < 4; ++r) {
          const size_t row = crow + 16 * mf + r;
          float x1 = acc[mf][nf2][r], x2 = acc[mf][nf2 + 2][r];
          dst[row * 64 + i]      = f2bf((x1 * cc[r] - x2 * ss[r]) * qs);
          dst[row * 64 + i + 32] = f2bf((x2 * cc[r] + x1 * ss[r]) * qs);
        }
      }
    }
  }
}

// ---------------- V transpose (bf16): Vt[g][d][s] = Vbuf[g][s][d] ----------------
__global__ __launch_bounds__(256) void vtrans_k(const ushort_t* __restrict__ Vbuf,
                                                ushort_t* __restrict__ Vt) {
  __shared__ ushort_t t[64][65];
  int s0 = blockIdx.x * 64, g = blockIdx.y;
  for (int idx = threadIdx.x; idx < 4096; idx += 256) {
    int r = idx >> 6, d = idx & 63;
    t[d][r] = Vbuf[((size_t)g * 2048 + s0 + r) * 64 + d];
  }
  __syncthreads();
  for (int idx = threadIdx.x; idx < 4096; idx += 256) {
    int d = idx >> 6, c = idx & 63;
    Vt[((size_t)g * 64 + d) * 2048 + s0 + c] = t[d][c];
  }
}

// ---------------- bf16 MFMA flash attention v9: fixed-max softmax ----------------
// (round-10-verified) P = exp2(S' - 12); lsum via ones-MFMA sums the SAME bf16 P
// as PV so scale/truncation bias cancels in O/lsum. No max-reduce, no rescale.
__global__ __launch_bounds__(256, 4) void attn9_k(const ushort_t* __restrict__ Qbf,
                                                  const ushort_t* __restrict__ Kbf,
                                                  const ushort_t* __restrict__ Vt,
                                                  ushort_t* __restrict__ outb) {
  __shared__ __align__(16) ushort_t Kl[2][64 * 64];
  __shared__ __align__(16) ushort_t Vl[2][64 * 64];
  __shared__ __align__(16) ushort_t Pl[4][1024];
  const int gh = blockIdx.x;
  const int y = blockIdx.y;
  const int bb = y & 7, aa = y >> 3;
  const int u = (aa == 0) ? 31 - bb : (aa == 1) ? 16 + bb : (aa == 2) ? 15 - bb : bb;
  const int g = gh >> 2;
  const int w = threadIdx.x >> 6, l = threadIdx.x & 63;
  const int li = l & 15, hi = l >> 4;
  const int q0 = 64 * u + 16 * w;
  const int nt = u + 1;

  const ushort_t* Qh = Qbf + (long)gh * 2048 * 64;
  const ushort_t* Kh = Kbf + (long)g * 2048 * 64;
  const ushort_t* Vh = Vt + (long)g * 64 * 2048;
  char* Pw = (char*)&Pl[w][0];

  const int sr = 16 * w + (l >> 3);
  const int sc = (l & 7) ^ (l >> 3);
  const short8 ones = {0x3F80, 0x3F80, 0x3F80, 0x3F80, 0x3F80, 0x3F80, 0x3F80, 0x3F80};

  short8 aq0 = *(const short8*)&Qh[(q0 + li) * 64 + hi * 8];
  short8 aq1 = *(const short8*)&Qh[(q0 + li) * 64 + 32 + hi * 8];

  f32x4 o[4];
#pragma unroll
  for (int df = 0; df < 4; ++df) o[df] = (f32x4){0.f, 0.f, 0.f, 0.f};
  f32x4 os = (f32x4){0.f, 0.f, 0.f, 0.f};   // row-sums via ones-column MFMA

  // prologue: stage tile 0 into buf 0
  GLDS16(Kh + (long)sr * 64 + sc * 8,         &Kl[0][(16 * w) * 64]);
  GLDS16(Kh + (long)(sr + 8) * 64 + sc * 8,   &Kl[0][(16 * w + 8) * 64]);
  GLDS16(Vh + (long)sr * 2048 + sc * 8,       &Vl[0][(16 * w) * 64]);
  GLDS16(Vh + (long)(sr + 8) * 2048 + sc * 8, &Vl[0][(16 * w + 8) * 64]);
  __syncthreads();

  int buf = 0;
  for (int it = 0; it < nt; ++it) {
    const int t0 = it * 64;
    if (it + 1 < nt) {  // prefetch next tile into buf^1 (stays in flight)
      const int tn = t0 + 64;
      GLDS16(Kh + (long)(tn + sr) * 64 + sc * 8,       &Kl[buf ^ 1][(16 * w) * 64]);
      GLDS16(Kh + (long)(tn + sr + 8) * 64 + sc * 8,   &Kl[buf ^ 1][(16 * w + 8) * 64]);
      GLDS16(Vh + (long)sr * 2048 + tn + sc * 8,       &Vl[buf ^ 1][(16 * w) * 64]);
      GLDS16(Vh + (long)(sr + 8) * 2048 + tn + sc * 8, &Vl[buf ^ 1][(16 * w + 8) * 64]);
    }
    const ushort_t* kb = &Kl[buf][0];
    const ushort_t* vb = &Vl[buf][0];

    // ---- QK^T: S'[16q][64t] (log2 domain) ----
    f32x4 sf[4];
#pragma unroll
    for (int f = 0; f < 4; ++f) sf[f] = (f32x4){0.f, 0.f, 0.f, 0.f};
    __builtin_amdgcn_s_setprio(1);
#pragma unroll
    for (int f = 0; f < 4; ++f) {
      const int row = 16 * f + li;
      short8 b0 = *(const short8*)&kb[row * 64 + ((hi ^ (row & 7)) << 3)];
      short8 b1 = *(const short8*)&kb[row * 64 + (((hi + 4) ^ (row & 7)) << 3)];
      mfma16(sf[f], aq0, b0);
      mfma16(sf[f], aq1, b1);
    }
    __builtin_amdgcn_s_setprio(0);

    // ---- causal mask (diagonal tile only) ----
    if (t0 + 63 > q0) {
#pragma unroll
      for (int f = 0; f < 4; ++f) {
        int t = t0 + 16 * f + li;
#pragma unroll
        for (int r = 0; r < 4; ++r)
          if (t > q0 + 4 * hi + r) sf[f][r] = -1e30f;
      }
    }
    // ---- fixed-max softmax: P = exp2(S' - 12), truncate-store to bf16 ----
#pragma unroll
    for (int f = 0; f < 4; ++f) {
      int k2 = 2 * (li + 16 * f);
#pragma unroll
      for (int r = 0; r < 4; ++r) {
        float p = __builtin_amdgcn_exp2f(sf[f][r] - FIXMAX);
        int q = 4 * hi + r;
        *(ushort_t*)(Pw + q * 128 + (k2 ^ ((q & 7) << 4))) =
            (ushort_t)(__builtin_bit_cast(unsigned, p) >> 16);
      }
    }

    // ---- PV: O[16q][64d] += P * V^T; row-sums accumulate via ones-frag ----
    __builtin_amdgcn_s_setprio(1);
#pragma unroll
    for (int kst = 0; kst < 2; ++kst) {
      short8 pa = *(const short8*)(Pw + li * 128 + (((4 * kst + hi) ^ (li & 7)) << 4));
#pragma unroll
      for (int df = 0; df < 4; ++df) {
        const int row = 16 * df + li;
        short8 bv = *(const short8*)&vb[row * 64 + (((4 * kst + hi) ^ (row & 7)) << 3)];
        mfma16(o[df], pa, bv);
      }
      mfma16(os, pa, ones);
    }
    __builtin_amdgcn_s_setprio(0);

    __syncthreads();  // drains GLDS (vmcnt) + all waves done reading buf
    buf ^= 1;
  }
  // ---- epilogue: normalize by ones-MFMA row-sums, store bf16 (RNE) ----
#pragma unroll
  for (int r = 0; r < 4; ++r) {
    float inv = 1.f / os[r];
#pragma unroll
    for (int df = 0; df < 4; ++df)
      outb[(long)(q0 + 4 * hi + r) * HID_DIM + gh * 64 + 16 * df + li] =
          f2bf(o[df][r] * inv);
  }
}

extern "C" void kernel_launch(void* const* d_in, const int* in_sizes, int n_in,
                              void* d_out, int out_size, void* d_ws, size_t ws_size,
                              hipStream_t stream) {
  const float* X    = (const float*)d_in[0];  // 2048x2048
  const float* cosb = (const float*)d_in[1];  // 2048x32
  const float* sinb = (const float*)d_in[2];  // 2048x32
  const float* Wqkv = (const float*)d_in[3];  // 2048x3072
  const float* Wd   = (const float*)d_in[4];  // 2048x2048
  float* out = (float*)d_out;                 // 2048x2048 fp32

  // workspace (all disjoint, ~51 MB)
  char* ws = (char*)d_ws;
  ushort_t* Xbf   = (ushort_t*)ws;                             // 8 MB
  ushort_t* WqkvT = Xbf + (size_t)2048 * 2048;                 // 12.6 MB
  ushort_t* WdT   = WqkvT + (size_t)3072 * 2048;               // 8 MB
  ushort_t* Qbf   = WdT + (size_t)2048 * 2048;                 // 8 MB
  ushort_t* Kbf   = Qbf + (size_t)32 * 2048 * 64;              // 2 MB
  ushort_t* Vbuf  = Kbf + (size_t)8 * 2048 * 64;               // 2 MB
  ushort_t* Vt    = Vbuf + (size_t)8 * 2048 * 64;              // 2 MB
  ushort_t* attnO = Vt + (size_t)8 * 2048 * 64;                // 8 MB
  float*    cosT  = (float*)(attnO + (size_t)2048 * 2048);     // 0.25 MB
  float*    sinT  = cosT + (size_t)32 * 2048;                  // 0.25 MB

  cvt_bf16_k<<<4096, 256, 0, stream>>>(X, Xbf, (2048 * 2048) / 4);
  tcvt_k<<<dim3(3072 / 32, 2048 / 32), 256, 0, stream>>>(Wqkv, WqkvT, 2048, 3072);
  tcvt_k<<<dim3(2048 / 32, 2048 / 32), 256, 0, stream>>>(Wd, WdT, 2048, 2048);
  cs_trans_k<<<256, 256, 0, stream>>>(cosb, sinb, cosT, sinT);

  // qkv GEMM (M=2048, N=3072, K=2048) with fused RoPE/bf16/head-major epilogue
  gemm_qkv_k<<<dim3(3072 / 128, 2048 / 128), 256, 0, stream>>>(
      Xbf, WqkvT, cosT, sinT, Qbf, Kbf, Vbuf, 2048, 3072, 2048);

  vtrans_k<<<dim3(S_LEN / 64, NG), 256, 0, stream>>>(Vbuf, Vt);

  attn9_k<<<dim3(NG * NHQ, 32), 256, 0, stream>>>(Qbf, Kbf, Vt, attnO);

  // out = attnO @ Wd  (M=2048, N=2048, K=2048)
  gemm_bt_k<<<dim3(2048 / 128, 2048 / 128), 256, 0, stream>>>(attnO, WdT, out,
                                                              2048, 2048, 2048);
}